// Round 1
// baseline (1376.227 us; speedup 1.0000x reference)
//
#include <hip/hip_runtime.h>
#include <hip/hip_bf16.h>

#define BATCH 8
#define L 2048
#define D 1024

// ws slot layout (float offsets). One slot per in-flight batch.
#define OFF_RMAX (L*L)
#define OFF_RINV (L*L + L)
#define OFF_CMAX (L*L + 2*L)
#define OFF_CINV (L*L + 3*L)
#define OFF_CPM  (L*L + 4*L)    // 16 partial col-max rows
#define OFF_CPS  (L*L + 20*L)   // 16 partial col-sum rows
#define SLOT_F   (L*L + 36*L)   // floats per slot (~17.07 MB)

typedef __attribute__((ext_vector_type(8))) short bf16x8;
typedef __attribute__((ext_vector_type(4))) float f32x4;

static __device__ inline unsigned short f2bf(float x) {
  union { float f; unsigned u; } v; v.f = x;
  unsigned r = v.u + 0x7fff + ((v.u >> 16) & 1);   // RNE (inputs are finite)
  return (unsigned short)(r >> 16);
}
static __device__ inline float bf2f(unsigned short h) {
  union { unsigned u; float f; } v; v.u = ((unsigned)h) << 16; return v.f;
}
static __device__ inline unsigned pack2(float x, float y) {
  return (unsigned)f2bf(x) | ((unsigned)f2bf(y) << 16);
}
// split x,y into hi bf16 pair and lo (residual) bf16 pair, packed as u32 each
static __device__ inline void split2(float x, float y, unsigned &hi, unsigned &lo) {
  unsigned short hx = f2bf(x), hy = f2bf(y);
  float rx = x - bf2f(hx), ry = y - bf2f(hy);
  hi = (unsigned)hx | ((unsigned)hy << 16);
  lo = (unsigned)f2bf(rx) | ((unsigned)f2bf(ry) << 16);
}

// ---------------------------------------------------------------------------
// Kernel 1: e = a @ b^T  (split-bf16: hh + hl + lh -> ~fp32 logit precision)
// 128x128 tile, BK=32, 4 waves (2x2), each wave 4x4 of 16x16x32 MFMA tiles.
// ---------------------------------------------------------------------------
__global__ __launch_bounds__(256) void k_gemm_e(const float* __restrict__ A,
                                                const float* __restrict__ Bm,
                                                float* __restrict__ ws, int b0) {
  const int bz = blockIdx.z, batch = b0 + bz;
  const float* a = A + (size_t)batch * L * D;
  const float* b = Bm + (size_t)batch * L * D;
  float* e = ws + (size_t)bz * SLOT_F;
  const int i0 = blockIdx.x * 128, j0 = blockIdx.y * 128;
  __shared__ unsigned short sAh[128][40], sAl[128][40];  // +8 pad: conflict-free b128 reads
  __shared__ unsigned short sBh[128][40], sBl[128][40];
  const int tid = threadIdx.x;
  const int lane = tid & 63, wave = tid >> 6;
  const int wm = (wave & 1) * 64, wn = (wave >> 1) * 64;
  const int q = lane >> 4, lr = lane & 15;
  f32x4 acc[4][4] = {};
  for (int k0 = 0; k0 < D; k0 += 32) {
    __syncthreads();
#pragma unroll
    for (int r = 0; r < 4; ++r) {
      int idx = tid + r * 256;          // 1024 float4 slots = 128 rows x 8
      int row = idx >> 3, c4 = (idx & 7) * 4;
      float4 va = *(const float4*)(a + (size_t)(i0 + row) * D + k0 + c4);
      float4 vb = *(const float4*)(b + (size_t)(j0 + row) * D + k0 + c4);
      unsigned h0, l0, h1, l1;
      split2(va.x, va.y, h0, l0); split2(va.z, va.w, h1, l1);
      *(uint2*)&sAh[row][c4] = make_uint2(h0, h1);
      *(uint2*)&sAl[row][c4] = make_uint2(l0, l1);
      split2(vb.x, vb.y, h0, l0); split2(vb.z, vb.w, h1, l1);
      *(uint2*)&sBh[row][c4] = make_uint2(h0, h1);
      *(uint2*)&sBl[row][c4] = make_uint2(l0, l1);
    }
    __syncthreads();
    bf16x8 fah[4], fal[4], fbh[4], fbl[4];
#pragma unroll
    for (int t = 0; t < 4; ++t) {
      fah[t] = *(const bf16x8*)&sAh[wm + t * 16 + lr][q * 8];
      fal[t] = *(const bf16x8*)&sAl[wm + t * 16 + lr][q * 8];
      fbh[t] = *(const bf16x8*)&sBh[wn + t * 16 + lr][q * 8];
      fbl[t] = *(const bf16x8*)&sBl[wn + t * 16 + lr][q * 8];
    }
#pragma unroll
    for (int mi = 0; mi < 4; ++mi)
#pragma unroll
      for (int ni = 0; ni < 4; ++ni) {
        acc[mi][ni] = __builtin_amdgcn_mfma_f32_16x16x32_bf16(fah[mi], fbh[ni], acc[mi][ni], 0, 0, 0);
        acc[mi][ni] = __builtin_amdgcn_mfma_f32_16x16x32_bf16(fah[mi], fbl[ni], acc[mi][ni], 0, 0, 0);
        acc[mi][ni] = __builtin_amdgcn_mfma_f32_16x16x32_bf16(fal[mi], fbh[ni], acc[mi][ni], 0, 0, 0);
      }
  }
  // C/D layout (verified m89/m91): col = lane&15, row = (lane>>4)*4 + reg
#pragma unroll
  for (int mi = 0; mi < 4; ++mi)
#pragma unroll
    for (int ni = 0; ni < 4; ++ni)
#pragma unroll
      for (int r = 0; r < 4; ++r)
        e[(size_t)(i0 + wm + mi * 16 + q * 4 + r) * L + (j0 + wn + ni * 16 + lr)] =
            acc[mi][ni][r];
}

// ---------------------------------------------------------------------------
// Row softmax stats: one block per row. Values kept in regs (8/thread).
// ---------------------------------------------------------------------------
__global__ __launch_bounds__(256) void k_rowstats(float* __restrict__ ws) {
  float* slot = ws + (size_t)blockIdx.y * SLOT_F;
  const int row = blockIdx.x, tid = threadIdx.x;
  const float* er = slot + (size_t)row * L;
  float v[8]; float m = -INFINITY;
#pragma unroll
  for (int r = 0; r < 8; ++r) { v[r] = er[tid + r * 256]; m = fmaxf(m, v[r]); }
  __shared__ float red[4];
#pragma unroll
  for (int o = 32; o; o >>= 1) m = fmaxf(m, __shfl_xor(m, o));
  if ((tid & 63) == 0) red[tid >> 6] = m;
  __syncthreads();
  m = fmaxf(fmaxf(red[0], red[1]), fmaxf(red[2], red[3]));
  float s = 0.f;
#pragma unroll
  for (int r = 0; r < 8; ++r) s += __expf(v[r] - m);
  __syncthreads();
#pragma unroll
  for (int o = 32; o; o >>= 1) s += __shfl_xor(s, o);
  if ((tid & 63) == 0) red[tid >> 6] = s;
  __syncthreads();
  if (tid == 0) {
    s = red[0] + red[1] + red[2] + red[3];
    slot[OFF_RMAX + row] = m;
    slot[OFF_RINV + row] = 1.0f / s;
  }
}

// ---------------------------------------------------------------------------
// Col softmax stats: online (m,s) per column over a 128-row stripe; coalesced.
// ---------------------------------------------------------------------------
__global__ __launch_bounds__(256) void k_colpart(float* __restrict__ ws) {
  float* slot = ws + (size_t)blockIdx.z * SLOT_F;
  const int j = blockIdx.x * 256 + threadIdx.x;
  const int i0 = blockIdx.y * 128;
  float m = -INFINITY, s = 0.f;
  for (int i = i0; i < i0 + 128; ++i) {
    float v = slot[(size_t)i * L + j];
    float nm = fmaxf(m, v);
    s = s * __expf(m - nm) + __expf(v - nm);
    m = nm;
  }
  slot[OFF_CPM + blockIdx.y * L + j] = m;
  slot[OFF_CPS + blockIdx.y * L + j] = s;
}

__global__ __launch_bounds__(256) void k_colmerge(float* __restrict__ ws) {
  float* slot = ws + (size_t)blockIdx.y * SLOT_F;
  const int j = blockIdx.x * 256 + threadIdx.x;
  float M = -INFINITY;
#pragma unroll
  for (int k = 0; k < 16; ++k) M = fmaxf(M, slot[OFF_CPM + k * L + j]);
  float S = 0.f;
#pragma unroll
  for (int k = 0; k < 16; ++k)
    S += slot[OFF_CPS + k * L + j] * __expf(slot[OFF_CPM + k * L + j] - M);
  slot[OFF_CMAX + j] = M;
  slot[OFF_CINV + j] = 1.0f / S;
}

// ---------------------------------------------------------------------------
// a_tilda[i,d] = sum_j softmax_row(e)[i,j] * b[j,d].  M=i, N=d, K=j.
// P computed on-the-fly from e; b staged transposed (sB[d][j]) for B-frags.
// ---------------------------------------------------------------------------
__global__ __launch_bounds__(256) void k_atilda(const float* __restrict__ Bm,
                                                float* __restrict__ ws,
                                                float* __restrict__ out, int b0) {
  const int bz = blockIdx.z, batch = b0 + bz;
  float* slot = ws + (size_t)bz * SLOT_F;
  const float* b = Bm + (size_t)batch * L * D;
  const int i0 = blockIdx.x * 128, d0 = blockIdx.y * 128;
  __shared__ unsigned short sP[128][40], sB[128][40];
  __shared__ float sRm[128], sRi[128];
  const int tid = threadIdx.x;
  if (tid < 128) { sRm[tid] = slot[OFF_RMAX + i0 + tid]; sRi[tid] = slot[OFF_RINV + i0 + tid]; }
  const int lane = tid & 63, wave = tid >> 6;
  const int wm = (wave & 1) * 64, wn = (wave >> 1) * 64;
  const int q = lane >> 4, lr = lane & 15;
  f32x4 acc[4][4] = {};
  for (int k0 = 0; k0 < L; k0 += 32) {
    __syncthreads();
#pragma unroll
    for (int r = 0; r < 4; ++r) {
      int idx = tid + r * 256;
      {  // P tile: 128 rows(i) x 32 cols(j)
        int row = idx >> 3, c4 = (idx & 7) * 4;
        float4 v = *(const float4*)(slot + (size_t)(i0 + row) * L + k0 + c4);
        float m = sRm[row], inv = sRi[row];
        *(uint2*)&sP[row][c4] = make_uint2(
            pack2(__expf(v.x - m) * inv, __expf(v.y - m) * inv),
            pack2(__expf(v.z - m) * inv, __expf(v.w - m) * inv));
      }
      {  // B tile: 32 rows(j) x 128 cols(d) -> transposed sB[d][j]
        int jr = idx >> 5, c4 = (idx & 31) * 4;
        float4 v = *(const float4*)(b + (size_t)(k0 + jr) * D + d0 + c4);
        sB[c4 + 0][jr] = f2bf(v.x);
        sB[c4 + 1][jr] = f2bf(v.y);
        sB[c4 + 2][jr] = f2bf(v.z);
        sB[c4 + 3][jr] = f2bf(v.w);
      }
    }
    __syncthreads();
    bf16x8 fa[4], fb[4];
#pragma unroll
    for (int t = 0; t < 4; ++t) {
      fa[t] = *(const bf16x8*)&sP[wm + t * 16 + lr][q * 8];
      fb[t] = *(const bf16x8*)&sB[wn + t * 16 + lr][q * 8];
    }
#pragma unroll
    for (int mi = 0; mi < 4; ++mi)
#pragma unroll
      for (int ni = 0; ni < 4; ++ni)
        acc[mi][ni] = __builtin_amdgcn_mfma_f32_16x16x32_bf16(fa[mi], fb[ni], acc[mi][ni], 0, 0, 0);
  }
  float* o = out + (size_t)batch * L * D;
#pragma unroll
  for (int mi = 0; mi < 4; ++mi)
#pragma unroll
    for (int ni = 0; ni < 4; ++ni)
#pragma unroll
      for (int r = 0; r < 4; ++r)
        o[(size_t)(i0 + wm + mi * 16 + q * 4 + r) * D + (d0 + wn + ni * 16 + lr)] =
            acc[mi][ni][r];
}

// ---------------------------------------------------------------------------
// b_tilda[j,d] = sum_i softmax_col(e)[i,j] * a[i,d].  M=j, N=d, K=i.
// Pc^T staged via transpose (sP[j][i]); a staged transposed (sB[d][i]).
// ---------------------------------------------------------------------------
__global__ __launch_bounds__(256) void k_btilda(const float* __restrict__ Am,
                                                float* __restrict__ ws,
                                                float* __restrict__ out, int b0) {
  const int bz = blockIdx.z, batch = b0 + bz;
  float* slot = ws + (size_t)bz * SLOT_F;
  const float* a = Am + (size_t)batch * L * D;
  const int j0 = blockIdx.x * 128, d0 = blockIdx.y * 128;
  __shared__ unsigned short sP[128][40], sB[128][40];
  __shared__ float sCm[128], sCi[128];
  const int tid = threadIdx.x;
  if (tid < 128) { sCm[tid] = slot[OFF_CMAX + j0 + tid]; sCi[tid] = slot[OFF_CINV + j0 + tid]; }
  const int lane = tid & 63, wave = tid >> 6;
  const int wm = (wave & 1) * 64, wn = (wave >> 1) * 64;
  const int q = lane >> 4, lr = lane & 15;
  f32x4 acc[4][4] = {};
  for (int k0 = 0; k0 < L; k0 += 32) {
    __syncthreads();
#pragma unroll
    for (int r = 0; r < 4; ++r) {
      int idx = tid + r * 256;
      int ir = idx >> 5, c4 = (idx & 31) * 4;  // 32 rows(i) x 128 cols
      {  // P tile: e[i0k+ir, j0+c4..] -> sP[j][i]
        float4 v = *(const float4*)(slot + (size_t)(k0 + ir) * L + j0 + c4);
        sP[c4 + 0][ir] = f2bf(__expf(v.x - sCm[c4 + 0]) * sCi[c4 + 0]);
        sP[c4 + 1][ir] = f2bf(__expf(v.y - sCm[c4 + 1]) * sCi[c4 + 1]);
        sP[c4 + 2][ir] = f2bf(__expf(v.z - sCm[c4 + 2]) * sCi[c4 + 2]);
        sP[c4 + 3][ir] = f2bf(__expf(v.w - sCm[c4 + 3]) * sCi[c4 + 3]);
      }
      {  // B tile: a[i0k+ir, d0+c4..] -> sB[d][i]
        float4 v = *(const float4*)(a + (size_t)(k0 + ir) * D + d0 + c4);
        sB[c4 + 0][ir] = f2bf(v.x);
        sB[c4 + 1][ir] = f2bf(v.y);
        sB[c4 + 2][ir] = f2bf(v.z);
        sB[c4 + 3][ir] = f2bf(v.w);
      }
    }
    __syncthreads();
    bf16x8 fa[4], fb[4];
#pragma unroll
    for (int t = 0; t < 4; ++t) {
      fa[t] = *(const bf16x8*)&sP[wm + t * 16 + lr][q * 8];
      fb[t] = *(const bf16x8*)&sB[wn + t * 16 + lr][q * 8];
    }
#pragma unroll
    for (int mi = 0; mi < 4; ++mi)
#pragma unroll
      for (int ni = 0; ni < 4; ++ni)
        acc[mi][ni] = __builtin_amdgcn_mfma_f32_16x16x32_bf16(fa[mi], fb[ni], acc[mi][ni], 0, 0, 0);
  }
  float* o = out + (size_t)BATCH * L * D + (size_t)batch * L * D;
#pragma unroll
  for (int mi = 0; mi < 4; ++mi)
#pragma unroll
    for (int ni = 0; ni < 4; ++ni)
#pragma unroll
      for (int r = 0; r < 4; ++r)
        o[(size_t)(j0 + wm + mi * 16 + q * 4 + r) * D + (d0 + wn + ni * 16 + lr)] =
            acc[mi][ni][r];
}

extern "C" void kernel_launch(void* const* d_in, const int* in_sizes, int n_in,
                              void* d_out, int out_size, void* d_ws, size_t ws_size,
                              hipStream_t stream) {
  const float* a = (const float*)d_in[0];
  const float* b = (const float*)d_in[1];
  float* out = (float*)d_out;
  float* ws = (float*)d_ws;
  const size_t slot_bytes = (size_t)SLOT_F * sizeof(float);
  int S = (int)(ws_size / slot_bytes);
  if (S > BATCH) S = BATCH;
  if (S < 1) S = 1;  // assume ws >= ~17.1 MB
  for (int b0 = 0; b0 < BATCH; b0 += S) {
    int nb = (BATCH - b0 < S) ? (BATCH - b0) : S;
    hipLaunchKernelGGL(k_gemm_e, dim3(16, 16, nb), dim3(256), 0, stream, a, b, ws, b0);
    hipLaunchKernelGGL(k_rowstats, dim3(L, nb), dim3(256), 0, stream, ws);
    hipLaunchKernelGGL(k_colpart, dim3(L / 256, 16, nb), dim3(256), 0, stream, ws);
    hipLaunchKernelGGL(k_colmerge, dim3(L / 256, nb), dim3(256), 0, stream, ws);
    hipLaunchKernelGGL(k_atilda, dim3(16, 8, nb), dim3(256), 0, stream, b, ws, out, b0);
    hipLaunchKernelGGL(k_btilda, dim3(16, 8, nb), dim3(256), 0, stream, a, ws, out, b0);
  }
}

// Round 2
// 963.828 us; speedup vs baseline: 1.4279x; 1.4279x over previous
//
#include <hip/hip_runtime.h>
#include <hip/hip_bf16.h>

#define BATCH 8
#define L 2048
#define D 1024

// ws layout: [ at: B*D*L bf16 ][ bt: B*D*L bf16 ][ slots... ]
// slot layout (floats): e (L*L) | eT (L*L) | RMAX,RINV,CMAX,CINV (4*L)
#define STAT   (2*L*L)
#define SLOT_F (2*L*L + 4*L)

typedef __attribute__((ext_vector_type(8))) short bf16x8;
typedef __attribute__((ext_vector_type(4))) float f32x4;

static __device__ inline unsigned short f2bf(float x) {
  union { float f; unsigned u; } v; v.f = x;
  unsigned r = v.u + 0x7fff + ((v.u >> 16) & 1);   // RNE (inputs finite)
  return (unsigned short)(r >> 16);
}
static __device__ inline float bf2f(unsigned short h) {
  union { unsigned u; float f; } v; v.u = ((unsigned)h) << 16; return v.f;
}
static __device__ inline unsigned pack2(float x, float y) {
  return (unsigned)f2bf(x) | ((unsigned)f2bf(y) << 16);
}
static __device__ inline void split2(float x, float y, unsigned &hi, unsigned &lo) {
  unsigned short hx = f2bf(x), hy = f2bf(y);
  float rx = x - bf2f(hx), ry = y - bf2f(hy);
  hi = (unsigned)hx | ((unsigned)hy << 16);
  lo = (unsigned)f2bf(rx) | ((unsigned)f2bf(ry) << 16);
}

// ---------------------------------------------------------------------------
// k_prep: at[b][d][i] = bf16(a[b][i][d]); bt likewise from b. 64x64 tiles,
// LDS stride 65 floats (odd dwords -> <=2-way conflicts on both sides).
// ---------------------------------------------------------------------------
__global__ __launch_bounds__(256) void k_prep(const float* __restrict__ A,
                                              const float* __restrict__ Bm,
                                              unsigned short* __restrict__ at,
                                              unsigned short* __restrict__ bt) {
  const int z = blockIdx.z, batch = z & 7;
  const float* src = (z < 8 ? A : Bm) + (size_t)batch * L * D;
  unsigned short* dst = (z < 8 ? at : bt) + (size_t)batch * D * L;
  const int i0 = blockIdx.x * 64, d0 = blockIdx.y * 64;
  __shared__ float sT[64][65];
  const int tid = threadIdx.x;
#pragma unroll
  for (int it = 0; it < 4; ++it) {
    int idx = tid + it * 256;
    int row = idx >> 4, c4 = (idx & 15) * 4;         // row=i_local, c4=d_local
    float4 v = *(const float4*)(src + (size_t)(i0 + row) * D + d0 + c4);
    sT[row][c4 + 0] = v.x; sT[row][c4 + 1] = v.y;
    sT[row][c4 + 2] = v.z; sT[row][c4 + 3] = v.w;
  }
  __syncthreads();
#pragma unroll
  for (int it = 0; it < 4; ++it) {
    int idx = tid + it * 256;
    int orow = idx >> 4, c4 = (idx & 15) * 4;        // orow=d_local, c4=i_local
    uint2 o = make_uint2(pack2(sT[c4 + 0][orow], sT[c4 + 1][orow]),
                         pack2(sT[c4 + 2][orow], sT[c4 + 3][orow]));
    *(uint2*)&dst[(size_t)(d0 + orow) * L + i0 + c4] = o;
  }
}

// ---------------------------------------------------------------------------
// k_etrans: eT = e^T (fp32), same stride-65 transpose. e at slot+0, eT at +L*L.
// ---------------------------------------------------------------------------
__global__ __launch_bounds__(256) void k_etrans(float* __restrict__ ws) {
  float* slot = ws + (size_t)blockIdx.z * SLOT_F;
  const int i0 = blockIdx.x * 64, j0 = blockIdx.y * 64;
  __shared__ float sT[64][65];
  const int tid = threadIdx.x;
#pragma unroll
  for (int it = 0; it < 4; ++it) {
    int idx = tid + it * 256;
    int row = idx >> 4, c4 = (idx & 15) * 4;
    float4 v = *(const float4*)(slot + (size_t)(i0 + row) * L + j0 + c4);
    sT[row][c4 + 0] = v.x; sT[row][c4 + 1] = v.y;
    sT[row][c4 + 2] = v.z; sT[row][c4 + 3] = v.w;
  }
  __syncthreads();
  float* eT = slot + (size_t)L * L;
#pragma unroll
  for (int it = 0; it < 4; ++it) {
    int idx = tid + it * 256;
    int orow = idx >> 4, c4 = (idx & 15) * 4;        // orow=j_local, c4=i_local
    float4 o;
    o.x = sT[c4 + 0][orow]; o.y = sT[c4 + 1][orow];
    o.z = sT[c4 + 2][orow]; o.w = sT[c4 + 3][orow];
    *(float4*)(eT + (size_t)(j0 + orow) * L + i0 + c4) = o;
  }
}

// ---------------------------------------------------------------------------
// Kernel 1: e = a @ b^T  (split-bf16: hh + hl + lh). Unchanged from R0.
// ---------------------------------------------------------------------------
__global__ __launch_bounds__(256) void k_gemm_e(const float* __restrict__ A,
                                                const float* __restrict__ Bm,
                                                float* __restrict__ ws, int b0) {
  const int bz = blockIdx.z, batch = b0 + bz;
  const float* a = A + (size_t)batch * L * D;
  const float* b = Bm + (size_t)batch * L * D;
  float* e = ws + (size_t)bz * SLOT_F;
  const int i0 = blockIdx.x * 128, j0 = blockIdx.y * 128;
  __shared__ unsigned short sAh[128][40], sAl[128][40];
  __shared__ unsigned short sBh[128][40], sBl[128][40];
  const int tid = threadIdx.x;
  const int lane = tid & 63, wave = tid >> 6;
  const int wm = (wave & 1) * 64, wn = (wave >> 1) * 64;
  const int q = lane >> 4, lr = lane & 15;
  f32x4 acc[4][4] = {};
  for (int k0 = 0; k0 < D; k0 += 32) {
    __syncthreads();
#pragma unroll
    for (int r = 0; r < 4; ++r) {
      int idx = tid + r * 256;
      int row = idx >> 3, c4 = (idx & 7) * 4;
      float4 va = *(const float4*)(a + (size_t)(i0 + row) * D + k0 + c4);
      float4 vb = *(const float4*)(b + (size_t)(j0 + row) * D + k0 + c4);
      unsigned h0, l0, h1, l1;
      split2(va.x, va.y, h0, l0); split2(va.z, va.w, h1, l1);
      *(uint2*)&sAh[row][c4] = make_uint2(h0, h1);
      *(uint2*)&sAl[row][c4] = make_uint2(l0, l1);
      split2(vb.x, vb.y, h0, l0); split2(vb.z, vb.w, h1, l1);
      *(uint2*)&sBh[row][c4] = make_uint2(h0, h1);
      *(uint2*)&sBl[row][c4] = make_uint2(l0, l1);
    }
    __syncthreads();
    bf16x8 fah[4], fal[4], fbh[4], fbl[4];
#pragma unroll
    for (int t = 0; t < 4; ++t) {
      fah[t] = *(const bf16x8*)&sAh[wm + t * 16 + lr][q * 8];
      fal[t] = *(const bf16x8*)&sAl[wm + t * 16 + lr][q * 8];
      fbh[t] = *(const bf16x8*)&sBh[wn + t * 16 + lr][q * 8];
      fbl[t] = *(const bf16x8*)&sBl[wn + t * 16 + lr][q * 8];
    }
#pragma unroll
    for (int mi = 0; mi < 4; ++mi)
#pragma unroll
      for (int ni = 0; ni < 4; ++ni) {
        acc[mi][ni] = __builtin_amdgcn_mfma_f32_16x16x32_bf16(fah[mi], fbh[ni], acc[mi][ni], 0, 0, 0);
        acc[mi][ni] = __builtin_amdgcn_mfma_f32_16x16x32_bf16(fah[mi], fbl[ni], acc[mi][ni], 0, 0, 0);
        acc[mi][ni] = __builtin_amdgcn_mfma_f32_16x16x32_bf16(fal[mi], fbh[ni], acc[mi][ni], 0, 0, 0);
      }
  }
#pragma unroll
  for (int mi = 0; mi < 4; ++mi)
#pragma unroll
    for (int ni = 0; ni < 4; ++ni)
#pragma unroll
      for (int r = 0; r < 4; ++r)
        e[(size_t)(i0 + wm + mi * 16 + q * 4 + r) * L + (j0 + wn + ni * 16 + lr)] =
            acc[mi][ni][r];
}

// ---------------------------------------------------------------------------
// Row softmax stats over mat rows (mat = e or eT). Writes max, 1/sum.
// ---------------------------------------------------------------------------
__global__ __launch_bounds__(256) void k_rowstats(float* __restrict__ ws,
                                                  int matOff, int statOff) {
  float* slot = ws + (size_t)blockIdx.y * SLOT_F;
  const int row = blockIdx.x, tid = threadIdx.x;
  const float* er = slot + matOff + (size_t)row * L;
  float v[8]; float m = -INFINITY;
#pragma unroll
  for (int r = 0; r < 8; ++r) { v[r] = er[tid + r * 256]; m = fmaxf(m, v[r]); }
  __shared__ float red[4];
#pragma unroll
  for (int o = 32; o; o >>= 1) m = fmaxf(m, __shfl_xor(m, o));
  if ((tid & 63) == 0) red[tid >> 6] = m;
  __syncthreads();
  m = fmaxf(fmaxf(red[0], red[1]), fmaxf(red[2], red[3]));
  float s = 0.f;
#pragma unroll
  for (int r = 0; r < 8; ++r) s += __expf(v[r] - m);
  __syncthreads();
#pragma unroll
  for (int o = 32; o; o >>= 1) s += __shfl_xor(s, o);
  if ((tid & 63) == 0) red[tid >> 6] = s;
  __syncthreads();
  if (tid == 0) {
    s = red[0] + red[1] + red[2] + red[3];
    slot[statOff + row] = m;
    slot[statOff + L + row] = 1.0f / s;
  }
}

// ---------------------------------------------------------------------------
// k_pv: out[m][d] = sum_k softmax_row(mat)[m][k] * W[k][d], W given as
// Wt[d][k] bf16 (pre-transposed). Used for a_tilda (mat=e, Wt=bt) and
// b_tilda (mat=eT, Wt=at). All LDS staging row-contiguous (no conflicts).
// ---------------------------------------------------------------------------
__global__ __launch_bounds__(256) void k_pv(const unsigned short* __restrict__ Wt,
                                            float* __restrict__ ws,
                                            int matOff, int statOff,
                                            float* __restrict__ outB, int b0) {
  const int bz = blockIdx.z, batch = b0 + bz;
  float* slot = ws + (size_t)bz * SLOT_F;
  const float* mat = slot + matOff;
  const unsigned short* W = Wt + (size_t)batch * D * L;
  const int m0 = blockIdx.x * 128, d0 = blockIdx.y * 128;
  __shared__ unsigned short sP[128][40], sB[128][40];
  __shared__ float sRm[128], sRi[128];
  const int tid = threadIdx.x;
  if (tid < 128) {
    sRm[tid] = slot[statOff + m0 + tid];
    sRi[tid] = slot[statOff + L + m0 + tid];
  }
  const int lane = tid & 63, wave = tid >> 6;
  const int wm = (wave & 1) * 64, wn = (wave >> 1) * 64;
  const int q = lane >> 4, lr = lane & 15;
  f32x4 acc[4][4] = {};
  for (int k0 = 0; k0 < L; k0 += 32) {
    __syncthreads();
#pragma unroll
    for (int r = 0; r < 4; ++r) {  // P tile: 128 rows(m) x 32 cols(k)
      int idx = tid + r * 256;
      int row = idx >> 3, c4 = (idx & 7) * 4;
      float4 v = *(const float4*)(mat + (size_t)(m0 + row) * L + k0 + c4);
      float m = sRm[row], inv = sRi[row];
      *(uint2*)&sP[row][c4] = make_uint2(
          pack2(__expf(v.x - m) * inv, __expf(v.y - m) * inv),
          pack2(__expf(v.z - m) * inv, __expf(v.w - m) * inv));
    }
#pragma unroll
    for (int r = 0; r < 2; ++r) {  // W tile: 128 rows(d) x 32 cols(k), uint4
      int idx = tid + r * 256;
      int dl = idx >> 2, k8 = (idx & 3) * 8;
      *(uint4*)&sB[dl][k8] =
          *(const uint4*)&W[(size_t)(d0 + dl) * L + k0 + k8];
    }
    __syncthreads();
    bf16x8 fa[4], fb[4];
#pragma unroll
    for (int t = 0; t < 4; ++t) {
      fa[t] = *(const bf16x8*)&sP[wm + t * 16 + lr][q * 8];
      fb[t] = *(const bf16x8*)&sB[wn + t * 16 + lr][q * 8];
    }
#pragma unroll
    for (int mi = 0; mi < 4; ++mi)
#pragma unroll
      for (int ni = 0; ni < 4; ++ni)
        acc[mi][ni] = __builtin_amdgcn_mfma_f32_16x16x32_bf16(fa[mi], fb[ni], acc[mi][ni], 0, 0, 0);
  }
  float* o = outB + (size_t)batch * L * D;
#pragma unroll
  for (int mi = 0; mi < 4; ++mi)
#pragma unroll
    for (int ni = 0; ni < 4; ++ni)
#pragma unroll
      for (int r = 0; r < 4; ++r)
        o[(size_t)(m0 + wm + mi * 16 + q * 4 + r) * D + (d0 + wn + ni * 16 + lr)] =
            acc[mi][ni][r];
}

extern "C" void kernel_launch(void* const* d_in, const int* in_sizes, int n_in,
                              void* d_out, int out_size, void* d_ws, size_t ws_size,
                              hipStream_t stream) {
  const float* a = (const float*)d_in[0];
  const float* b = (const float*)d_in[1];
  float* out = (float*)d_out;
  unsigned short* at = (unsigned short*)d_ws;
  unsigned short* bt = at + (size_t)BATCH * D * L;
  float* slots = (float*)(bt + (size_t)BATCH * D * L);
  const size_t wt_bytes = (size_t)2 * BATCH * D * L * 2;
  const size_t slot_bytes = (size_t)SLOT_F * sizeof(float);
  int S = 1;
  if (ws_size > wt_bytes + slot_bytes)
    S = (int)((ws_size - wt_bytes) / slot_bytes);
  if (S > BATCH) S = BATCH;
  if (S < 1) S = 1;

  hipLaunchKernelGGL(k_prep, dim3(L / 64, D / 64, 2 * BATCH), dim3(256), 0, stream,
                     a, b, at, bt);
  for (int b0 = 0; b0 < BATCH; b0 += S) {
    int nb = (BATCH - b0 < S) ? (BATCH - b0) : S;
    hipLaunchKernelGGL(k_gemm_e, dim3(16, 16, nb), dim3(256), 0, stream, a, b, slots, b0);
    hipLaunchKernelGGL(k_etrans, dim3(32, 32, nb), dim3(256), 0, stream, slots);
    hipLaunchKernelGGL(k_rowstats, dim3(L, nb), dim3(256), 0, stream, slots, 0, STAT);
    hipLaunchKernelGGL(k_rowstats, dim3(L, nb), dim3(256), 0, stream, slots, L * L, STAT + 2 * L);
    hipLaunchKernelGGL(k_pv, dim3(16, 8, nb), dim3(256), 0, stream,
                       bt, slots, 0, STAT, out, b0);
    hipLaunchKernelGGL(k_pv, dim3(16, 8, nb), dim3(256), 0, stream,
                       at, slots, L * L, STAT + 2 * L, out + (size_t)BATCH * L * D, b0);
  }
}